// Round 4
// baseline (106.963 us; speedup 1.0000x reference)
//
#include <hip/hip_runtime.h>
#include <hip/hip_bf16.h>
#include <math.h>

// TransitionLoss on MI355X (gfx950), v4.
// Loss per anchor depends only on (target,sub) -> <=64 distinct pairs (4x dedup).
// For pair p, part (neg/pos): tr[r,c] = (E[r]*F[c])^2 * G[r,c], G = X X^T,
// X[a,k] = exp(sim[a,ik]-q[k]-w[a]) fp16, q[k]=(cm+ln scol)/2 from a row-scan
// stats table M,L[64][256] (every stat = masked max/logsum of ONE sim row).
// Pipeline: sim -> list -> stats -> buildX -> gram(MFMA) -> final. No atomics.

constexpr int kB = 256;
constexpr int kD = 512;
constexpr float NEG_BIG = -3.4e38f;

typedef _Float16 f16x8 __attribute__((ext_vector_type(8)));
typedef float f32x16 __attribute__((ext_vector_type(16)));

// ws byte offsets (all 16B-aligned where vector-loaded)
constexpr int O_SIM   = 0;                    // 256*256 f32
constexpr int O_M     = 262144;               // [64][256] f32
constexpr int O_L     = 327680;               // [64][256] f32
constexpr int O_IDX   = 393216;               // [64][4][256] u16
constexpr int O_CNT   = 524288;               // [64] int4
constexpr int O_METAI = 525312;               // [128] int4 {nR,nK,SKh,KP}
constexpr int O_METAS = 527360;               // [128] f32 scale
constexpr int O_E     = 527872;               // [128][256] f32
constexpr int O_F     = 658944;               // [128][256] f32
constexpr int O_PART  = 790016;               // [8192] f32
constexpr int O_X     = 822784;               // [128][256*264] fp16 (~17.3 MB)
constexpr int XSTRIDE = 256 * 264;            // halves per (pair,part) slot

// ---------------- sim = f @ f^T (16x16 tiles) ----------------
__global__ __launch_bounds__(256)
void simKernel(const float* __restrict__ f, float* __restrict__ sim) {
  __shared__ float As[16][68];
  __shared__ float Bs[16][68];
  const int tid = threadIdx.x;
  const int tx = tid & 15, ty = tid >> 4;
  const int lr = tid >> 4, lc4 = (tid & 15) * 4;
  const int rowBase = blockIdx.y * 16, colBase = blockIdx.x * 16;
  float a0 = 0.f, a1 = 0.f, a2 = 0.f, a3 = 0.f;
  for (int k0 = 0; k0 < kD; k0 += 64) {
    float4 va = *(const float4*)&f[(rowBase + lr) * kD + k0 + lc4];
    float4 vb = *(const float4*)&f[(colBase + lr) * kD + k0 + lc4];
    *(float4*)&As[lr][lc4] = va;
    *(float4*)&Bs[lr][lc4] = vb;
    __syncthreads();
#pragma unroll
    for (int kk = 0; kk < 64; kk += 16) {
      float4 x0 = *(const float4*)&As[ty][kk];
      float4 y0 = *(const float4*)&Bs[tx][kk];
      a0 = fmaf(x0.x, y0.x, a0); a0 = fmaf(x0.y, y0.y, a0);
      a0 = fmaf(x0.z, y0.z, a0); a0 = fmaf(x0.w, y0.w, a0);
      float4 x1 = *(const float4*)&As[ty][kk + 4];
      float4 y1 = *(const float4*)&Bs[tx][kk + 4];
      a1 = fmaf(x1.x, y1.x, a1); a1 = fmaf(x1.y, y1.y, a1);
      a1 = fmaf(x1.z, y1.z, a1); a1 = fmaf(x1.w, y1.w, a1);
      float4 x2 = *(const float4*)&As[ty][kk + 8];
      float4 y2 = *(const float4*)&Bs[tx][kk + 8];
      a2 = fmaf(x2.x, y2.x, a2); a2 = fmaf(x2.y, y2.y, a2);
      a2 = fmaf(x2.z, y2.z, a2); a2 = fmaf(x2.w, y2.w, a2);
      float4 x3 = *(const float4*)&As[ty][kk + 12];
      float4 y3 = *(const float4*)&Bs[tx][kk + 12];
      a3 = fmaf(x3.x, y3.x, a3); a3 = fmaf(x3.y, y3.y, a3);
      a3 = fmaf(x3.z, y3.z, a3); a3 = fmaf(x3.w, y3.w, a3);
    }
    __syncthreads();
  }
  sim[(rowBase + ty) * kB + colBase + tx] = (a0 + a1) + (a2 + a3);
}

// ---------------- per-pair category lists + meta (1 wave/pair) ----------------
__global__ __launch_bounds__(64)
void listKernel(const int* __restrict__ tgt, const int* __restrict__ sub,
                unsigned short* __restrict__ idxAll, int* __restrict__ cnt4,
                int4* __restrict__ metaI, float* __restrict__ metaS) {
  const int p = blockIdx.x, t = p >> 1, s = p & 1;
  const int lane = threadIdx.x;
  __shared__ unsigned char cat[256];
  __shared__ int cnts[4];
  for (int chunk = 0; chunk < 4; chunk++) {
    int c = chunk * 64 + lane;
    bool pos = (tgt[c] == t), intra = (sub[c] == s);
    cat[c] = (unsigned char)(pos ? (intra ? 0 : 1) : (intra ? 2 : 3)); // mpi mpc mni mnc
  }
  __syncthreads();
  for (int l = 0; l < 4; l++) {
    int base = 0;
    for (int chunk = 0; chunk < 4; chunk++) {
      int c = chunk * 64 + lane;
      bool fl = (cat[c] == (unsigned char)l);
      unsigned long long mm = __ballot(fl);
      if (fl) {
        int pfx = __popcll(mm & ((1ull << lane) - 1ull));
        idxAll[(p * 4 + l) * 256 + base + pfx] = (unsigned short)c;
      }
      base += __popcll(mm);
    }
    if (lane == 0) cnts[l] = base;
  }
  __syncthreads();
  if (lane == 0) {
    cnt4[p * 4 + 0] = cnts[0]; cnt4[p * 4 + 1] = cnts[1];
    cnt4[p * 4 + 2] = cnts[2]; cnt4[p * 4 + 3] = cnts[3];
    const int mult = cnts[0];
#pragma unroll
    for (int part = 0; part < 2; part++) {
      int nR = part ? cnts[0] : cnts[2];
      int nK = part ? cnts[1] : cnts[3];
      int KP = (nK + 15) & ~15;
      int4 mi; mi.x = nR; mi.y = nK; mi.z = KP + 8; mi.w = KP;
      metaI[p * 2 + part] = mi;
      metaS[p * 2 + part] = (mult > 0 && nR > 0 && nK > 0)
                              ? (float)mult / ((float)nR * (float)nR) : 0.f;
    }
  }
}

// ---------------- stats: masked max/logsum of row a per pair ----------------
__global__ __launch_bounds__(512)
void statsKernel(const float* __restrict__ sim, const int* __restrict__ tgt,
                 const int* __restrict__ sub, float* __restrict__ Mv,
                 float* __restrict__ Lv) {
  const int a = blockIdx.x;
  const int lane = threadIdx.x & 63, wave = threadIdx.x >> 6;
  const float4 v4 = ((const float4*)(sim + a * kB))[lane];
  const int4 t4 = ((const int4*)tgt)[lane];
  const int4 s4 = ((const int4*)sub)[lane];
  const int ta = tgt[a], sa = sub[a];
  for (int jj = 0; jj < 8; jj++) {
    const int p = wave * 8 + jj, t = p >> 1, s = p & 1;
    const bool pa = (ta == t), ia = (sa == s);
    // selected col c: same pos-group as a, opposite intra-group (complement set)
    const bool e0 = ((t4.x == t) == pa) && ((s4.x == s) != ia);
    const bool e1 = ((t4.y == t) == pa) && ((s4.y == s) != ia);
    const bool e2 = ((t4.z == t) == pa) && ((s4.z == s) != ia);
    const bool e3 = ((t4.w == t) == pa) && ((s4.w == s) != ia);
    float m = fmaxf(fmaxf(e0 ? v4.x : NEG_BIG, e1 ? v4.y : NEG_BIG),
                    fmaxf(e2 ? v4.z : NEG_BIG, e3 ? v4.w : NEG_BIG));
#pragma unroll
    for (int o = 32; o >= 1; o >>= 1) m = fmaxf(m, __shfl_xor(m, o, 64));
    float ss = (e0 ? __expf(v4.x - m) : 0.f) + (e1 ? __expf(v4.y - m) : 0.f)
             + (e2 ? __expf(v4.z - m) : 0.f) + (e3 ? __expf(v4.w - m) : 0.f);
#pragma unroll
    for (int o = 32; o >= 1; o >>= 1) ss += __shfl_xor(ss, o, 64);
    if (lane == 0) { Mv[p * 256 + a] = m; Lv[p * 256 + a] = __logf(ss); }
  }
}

// ---------------- build X fp16 + E,F (pair x part x 4 row-slices) ----------------
__global__ __launch_bounds__(512)
void buildXKernel(const float* __restrict__ sim, const float* __restrict__ Mv,
                  const float* __restrict__ Lv, const unsigned short* __restrict__ idxAll,
                  const int4* __restrict__ metaI, const float* __restrict__ metaS,
                  _Float16* __restrict__ X, float* __restrict__ E, float* __restrict__ F) {
  const int b = blockIdx.x, pp = b >> 2, slice = b & 3;
  const int p = pp >> 1, part = pp & 1;
  if (metaS[pp] == 0.f) return;                 // absent pair / empty R or K
  const int4 mi = metaI[pp];
  const int nR = mi.x, nK = mi.y, SKh = mi.z, KP = mi.w;
  const unsigned short* iR = idxAll + (p * 4 + (part ? 0 : 2)) * 256;
  const unsigned short* iK = idxAll + (p * 4 + (part ? 1 : 3)) * 256;
  __shared__ float qs[256];
  __shared__ unsigned short iks[256];
  const int tid = threadIdx.x, lane = tid & 63, wave = tid >> 6;
  if (tid < 256) {
    int ik = (tid < nK) ? (int)iK[tid] : 0;
    iks[tid] = (unsigned short)ik;
    qs[tid] = (tid < nK) ? 0.5f * (Mv[p * 256 + ik] + Lv[p * 256 + ik]) : 0.f;
  }
  __syncthreads();
  _Float16* Xp = X + pp * XSTRIDE;
  for (int r = slice * 8 + wave; r < nR; r += 32) {
    const int a = (int)iR[r];
    const float* srow = sim + a * kB;
    float vals[4];
    float w = NEG_BIG;
#pragma unroll
    for (int j = 0; j < 4; j++) {
      int k = lane + 64 * j;
      float v = NEG_BIG;
      if (k < nK) v = srow[(int)iks[k]] - qs[k];
      vals[j] = v;
      w = fmaxf(w, v);
    }
#pragma unroll
    for (int o = 32; o >= 1; o >>= 1) w = fmaxf(w, __shfl_xor(w, o, 64));
#pragma unroll
    for (int j = 0; j < 4; j++) {
      int k = lane + 64 * j;
      if (k < KP) Xp[r * SKh + k] = (_Float16)__expf(vals[j] - w);  // pad k -> 0
    }
    if (lane == 0) {
      float u = Mv[p * 256 + a] + Lv[p * 256 + a];
      E[pp * 256 + r] = __expf(0.5f * (w - u));
      F[pp * 256 + r] = __expf(0.5f * w);
    }
  }
}

// ---------------- G = X X^T tiles (MFMA) + loss eval; 1 wave = 1 tile ----------------
__global__ __launch_bounds__(256)
void gramKernel(const _Float16* __restrict__ X, const float* __restrict__ E,
                const float* __restrict__ F, const int4* __restrict__ metaI,
                const float* __restrict__ metaS, float* __restrict__ partials) {
  const int lane = threadIdx.x & 63, wave = threadIdx.x >> 6;
  const int job = blockIdx.x * 4 + wave;
  const int pp = job >> 6, tile = job & 63;
  const int4 mi = metaI[pp];
  const int nR = mi.x, SKh = mi.z, KP = mi.w;
  const int r0 = (tile >> 3) << 5, c0 = (tile & 7) << 5;
  const float scale = metaS[pp];
  float res = 0.f;
  if (scale != 0.f && r0 < nR && c0 < nR) {
    const _Float16* Xp = X + pp * XSTRIDE;
    const int l31 = lane & 31, kg = lane >> 5;
    const _Float16* pa = Xp + (r0 + l31) * SKh + 8 * kg;
    const _Float16* pb = Xp + (c0 + l31) * SKh + 8 * kg;
    f32x16 acc;
#pragma unroll
    for (int g = 0; g < 16; g++) acc[g] = 0.f;
    for (int kb = 0; kb < KP; kb += 16) {
      f16x8 av = *(const f16x8*)(pa + kb);
      f16x8 bv = *(const f16x8*)(pb + kb);
      acc = __builtin_amdgcn_mfma_f32_32x32x16_f16(av, bv, acc, 0, 0, 0);
    }
    const int c = c0 + l31;
    if (c < nR) {
      const float Fc = F[pp * 256 + c];
      const int rb = r0 + 4 * kg;
      const bool neg = ((pp & 1) == 0);
#pragma unroll
      for (int g = 0; g < 16; g++) {
        const int r = rb + (g & 3) + ((g >> 2) << 3);  // C/D: col=lane&31, row=(g&3)+8(g>>2)+4(lane>>5)
        if (r < nR) {
          float x = E[pp * 256 + r] * Fc * sqrtf(acc[g]);   // sqrt(tr), exact factorization
          x = fmaxf(x, 1e-6f);                              // tr clip 1e-12
          res += neg ? fmaxf(x - 0.2f, 0.f) : fmaxf(0.5f - x, 0.f);
        }
      }
    }
  }
#pragma unroll
  for (int o = 32; o >= 1; o >>= 1) res += __shfl_xor(res, o, 64);
  if (lane == 0) partials[job] = res * scale;
}

// ---------------- deterministic final reduce + analytic empty-K terms ----------------
__global__ __launch_bounds__(1024)
void finalKernel(const float* __restrict__ partials, const int* __restrict__ cnt4,
                 float* __restrict__ out) {
  const int tid = threadIdx.x;
  float s = 0.f;
#pragma unroll
  for (int j = 0; j < 8; j++) s += partials[tid + 1024 * j];
  if (tid < 64) {
    int c0 = cnt4[tid * 4 + 0], c1 = cnt4[tid * 4 + 1];
    if (c0 > 0 && c1 == 0) s += (float)c0 * (0.5f - 1e-6f);  // pos part, empty K: x=1e-6
  }
#pragma unroll
  for (int o = 32; o >= 1; o >>= 1) s += __shfl_xor(s, o, 64);
  __shared__ float red[16];
  if ((tid & 63) == 0) red[tid >> 6] = s;
  __syncthreads();
  if (tid == 0) {
    float t = 0.f;
    for (int w = 0; w < 16; w++) t += red[w];
    out[0] = t * (1.0f / 256.0f);
  }
}

extern "C" void kernel_launch(void* const* d_in, const int* in_sizes, int n_in,
                              void* d_out, int out_size, void* d_ws, size_t ws_size,
                              hipStream_t stream) {
  (void)in_sizes; (void)n_in; (void)out_size; (void)ws_size;
  const float* feature = (const float*)d_in[0];
  const int* subv = (const int*)d_in[1];
  const int* tgtv = (const int*)d_in[2];
  float* out = (float*)d_out;
  char* ws = (char*)d_ws;

  float* sim = (float*)(ws + O_SIM);
  float* Mv = (float*)(ws + O_M);
  float* Lv = (float*)(ws + O_L);
  unsigned short* idxAll = (unsigned short*)(ws + O_IDX);
  int* cnt4 = (int*)(ws + O_CNT);
  int4* metaI = (int4*)(ws + O_METAI);
  float* metaS = (float*)(ws + O_METAS);
  float* E = (float*)(ws + O_E);
  float* F = (float*)(ws + O_F);
  float* partials = (float*)(ws + O_PART);
  _Float16* X = (_Float16*)(ws + O_X);

  simKernel<<<dim3(16, 16), 256, 0, stream>>>(feature, sim);
  listKernel<<<64, 64, 0, stream>>>(tgtv, subv, idxAll, cnt4, metaI, metaS);
  statsKernel<<<256, 512, 0, stream>>>(sim, tgtv, subv, Mv, Lv);
  buildXKernel<<<512, 512, 0, stream>>>(sim, Mv, Lv, idxAll, metaI, metaS, X, E, F);
  gramKernel<<<2048, 256, 0, stream>>>(X, E, F, metaI, metaS, partials);
  finalKernel<<<1, 1024, 0, stream>>>(partials, cnt4, out);
}